// Round 15
// baseline (267.187 us; speedup 1.0000x reference)
//
#include <hip/hip_runtime.h>
#include <hip/hip_cooperative_groups.h>
#include <math.h>

namespace cg = cooperative_groups;

#define S_LEN 1024
#define BATCH 2
#define DM 512
#define DI 1024
#define DS 128
#define DTR 32
#define CL 64            // chunk length
#define NC (S_LEN / CL)  // 16 chunks

typedef unsigned short ushortT;
typedef __attribute__((ext_vector_type(8))) short short8;
typedef __attribute__((ext_vector_type(4))) float f32x4;

__device__ __forceinline__ ushortT f2b(float f) {
  unsigned u = __builtin_bit_cast(unsigned, f);
  unsigned r = (u + 0x7fff + ((u >> 16) & 1)) >> 16;  // RNE
  return (ushortT)r;
}
__device__ __forceinline__ float b2f(ushortT h) {
  return __builtin_bit_cast(float, (unsigned)h << 16);
}

#define GLOAD16(g, l)                                                     \
  __builtin_amdgcn_global_load_lds(                                       \
      (const __attribute__((address_space(1))) void*)(g),                 \
      (__attribute__((address_space(3))) void*)(l), 16, 0, 0)

// ---- gemm64: 64x64 tile, 4 waves (2x2, each 32x32), XCD-swizzled flat grid,
// double-buffered LDS. MODE 0: fp32 out; 1: bf16 out.
template<int MODE>
__global__ __launch_bounds__(256) void gemm64(
    const ushortT* __restrict__ A, const ushortT* __restrict__ Bt,
    void* __restrict__ Cout, int N, int K, int ldc, int nbx) {
  __shared__ ushortT As[2][64 * 32];
  __shared__ ushortT Bs[2][64 * 32];
  const int nwg = gridDim.x;
  const int bid = blockIdx.x;
  const int flat = (bid & 7) * (nwg >> 3) + (bid >> 3);
  const int bxi = flat % nbx, byi = flat / nbx;
  const int bm = byi * 64, bn = bxi * 64;
  const int tid = threadIdx.x;
  const int l = tid & 63, w = tid >> 6;
  const int wr = w >> 1, wc = w & 1;
  const int srow = tid >> 2, scol = (tid & 3) * 8;
  const ushortT* gA = A + (size_t)(bm + srow) * K + scol;
  const ushortT* gB = Bt + (size_t)(bn + srow) * K + scol;
  f32x4 acc[2][2] = {};
  const int nt = K >> 5;
  GLOAD16(gA, &As[0][(size_t)tid * 8]);
  GLOAD16(gB, &Bs[0][(size_t)tid * 8]);
  __syncthreads();
  int cur = 0;
  for (int t = 0; t < nt; ++t) {
    if (t + 1 < nt) {
      GLOAD16(gA + (t + 1) * 32, &As[cur ^ 1][(size_t)tid * 8]);
      GLOAD16(gB + (t + 1) * 32, &Bs[cur ^ 1][(size_t)tid * 8]);
    }
    short8 a[2], b[2];
#pragma unroll
    for (int m = 0; m < 2; ++m)
      a[m] = *(const short8*)&As[cur][(wr * 32 + m * 16 + (l & 15)) * 32 + (l >> 4) * 8];
#pragma unroll
    for (int n = 0; n < 2; ++n)
      b[n] = *(const short8*)&Bs[cur][(wc * 32 + n * 16 + (l & 15)) * 32 + (l >> 4) * 8];
#pragma unroll
    for (int m = 0; m < 2; ++m)
#pragma unroll
      for (int n = 0; n < 2; ++n)
        acc[m][n] = __builtin_amdgcn_mfma_f32_16x16x32_bf16(a[m], b[n], acc[m][n], 0, 0, 0);
    __syncthreads();
    cur ^= 1;
  }
#pragma unroll
  for (int m = 0; m < 2; ++m) {
    int grow = bm + wr * 32 + m * 16 + (l >> 4) * 4;
#pragma unroll
    for (int n = 0; n < 2; ++n) {
      int gcol = bn + wc * 32 + n * 16 + (l & 15);
      if (gcol >= N) continue;
#pragma unroll
      for (int i = 0; i < 4; ++i) {
        float v = acc[m][n][i];
        if (MODE == 1)
          ((ushortT*)Cout)[(size_t)(grow + i) * ldc + gcol] = f2b(v);
        else
          ((float*)Cout)[(size_t)(grow + i) * ldc + gcol] = v;
      }
    }
  }
}

// ---- prep_all: weight transposes (fp32->bf16, [K,N]->[Npad,K], ushort2
// stores) + x cvt.
__global__ __launch_bounds__(256) void prep_all(
    const float* __restrict__ W_in, const float* __restrict__ W_x,
    const float* __restrict__ W_out, const float* __restrict__ x,
    ushortT* __restrict__ Wt_in, ushortT* __restrict__ Wt_x,
    ushortT* __restrict__ Wt_out, ushortT* __restrict__ x_bf) {
  __shared__ float tb[32][33];
  int bid = blockIdx.x;
  int tx = threadIdx.x, ty = threadIdx.y;  // (32,8)
  const float* in; ushortT* out; int K, N, bx, by;
  if (bid < 1024)      { in = W_in;  out = Wt_in;  K = 512;  N = 2048; bx = bid & 63; by = bid >> 6; }
  else if (bid < 1408) { int t2 = bid - 1024; in = W_x;   out = Wt_x;   K = 1024; N = 288;  bx = t2 % 12; by = t2 / 12; }
  else if (bid < 1920) { int t2 = bid - 1408; in = W_out; out = Wt_out; K = 1024; N = 512;  bx = t2 % 16; by = t2 / 16; }
  else {
    int i = (bid - 1920) * 256 + ty * 32 + tx;
    float4 v = ((const float4*)x)[i];
    ushort4 o; o.x = f2b(v.x); o.y = f2b(v.y); o.z = f2b(v.z); o.w = f2b(v.w);
    ((ushort4*)x_bf)[i] = o;
    return;
  }
  int n0 = bx * 32, k0 = by * 32;
  int flat = ty * 32 + tx;
  if (n0 < N) {
#pragma unroll
    for (int i = 0; i < 4; ++i)
      tb[ty + 8 * i][tx] = in[(size_t)(k0 + ty + 8 * i) * N + n0 + tx];
    __syncthreads();
#pragma unroll
    for (int j = 0; j < 2; ++j) {
      int idx = j * 256 + flat;        // 0..511
      int r = idx >> 4, c2 = idx & 15;
      ushort2 o;
      o.x = f2b(tb[2 * c2][r]);
      o.y = f2b(tb[2 * c2 + 1][r]);
      *(ushort2*)&out[(size_t)(n0 + r) * K + k0 + 2 * c2] = o;
    }
  } else {
    ushort2 z; z.x = 0; z.y = 0;
#pragma unroll
    for (int j = 0; j < 2; ++j) {
      int idx = j * 256 + flat;
      int r = idx >> 4, c2 = idx & 15;
      *(ushort2*)&out[(size_t)(n0 + r) * K + k0 + 2 * c2] = z;
    }
  }
}

// ---- depthwise causal conv, 4 d per thread (ushort4) ------------------------
__global__ __launch_bounds__(256) void conv_kernel(
    const ushortT* __restrict__ xr, const float* __restrict__ w,
    const float* __restrict__ b, ushortT* __restrict__ u) {
  int idx = blockIdx.x * blockDim.x + threadIdx.x;
  int g = idx & 255;
  int s = (idx >> 8) & (S_LEN - 1);
  int bb = idx >> 18;
  int d = g * 4;
  float4 bias = *(const float4*)&b[d];
  float4 w0 = *(const float4*)&w[(d + 0) * 4];
  float4 w1 = *(const float4*)&w[(d + 1) * 4];
  float4 w2 = *(const float4*)&w[(d + 2) * 4];
  float4 w3 = *(const float4*)&w[(d + 3) * 4];
  float a0 = bias.x, a1 = bias.y, a2 = bias.z, a3 = bias.w;
  const ushortT* xs = xr + (size_t)(bb * S_LEN) * (2 * DI) + d;
#pragma unroll
  for (int k = 0; k < 4; ++k) {
    int si = s - 3 + k;
    if (si >= 0) {
      ushort4 v = *(const ushort4*)&xs[(size_t)si * (2 * DI)];
      float wk0 = ((const float*)&w0)[k], wk1 = ((const float*)&w1)[k];
      float wk2 = ((const float*)&w2)[k], wk3 = ((const float*)&w3)[k];
      a0 = fmaf(b2f(v.x), wk0, a0);
      a1 = fmaf(b2f(v.y), wk1, a1);
      a2 = fmaf(b2f(v.z), wk2, a2);
      a3 = fmaf(b2f(v.w), wk3, a3);
    }
  }
  ushort4 o; o.x = f2b(a0); o.y = f2b(a1); o.z = f2b(a2); o.w = f2b(a3);
  *(ushort4*)&u[(size_t)idx * 4] = o;
}

// ---- scan_fused (cooperative, 512 blocks = 2/CU co-resident):
// phase1 = dt-proj + cumprod + ut + Z (ut,D stay in LDS; zb + dend to global)
//        + B/C staging + G while waiting; grid.sync
// phase2 = chunk-boundary chain zb->hstb; grid.sync
// phase3 = Y = D*(G@ut + C@hstb) + res, with ut/D read from LDS.
__global__ __launch_bounds__(256) void scan_fused(
    const float* __restrict__ dbl, const float* __restrict__ W_dt,
    const float* __restrict__ b_dt, const ushortT* __restrict__ u_bf,
    float* __restrict__ dend, ushortT* __restrict__ zb,
    ushortT* __restrict__ hstb, const ushortT* __restrict__ xr_bf,
    ushortT* __restrict__ yr) {
  __shared__ float   Dl[64][66];    // persistent: cumprod D, [d][s] fp32
  __shared__ ushortT utl[64][72];   // persistent: ut[d][s]
  __shared__ __align__(16) char ovl[45056];  // overlay region
  // phase1 views
  ushortT (*Btl)[72] = (ushortT(*)[72])ovl;            // 128x72x2 = 18432
  float   (*dtl)[36] = (float(*)[36])(ovl + 18432);    // 64x36x4  = 9216
  ushortT (*Wl)[68]  = (ushortT(*)[68])(ovl + 27648);  // 32x68x2  = 4352
  // phase3 views
  ushortT (*Cl)[136] = (ushortT(*)[136])ovl;           // 17408
  ushortT (*Bl)[136] = (ushortT(*)[136])(ovl + 17408); // 17408 (later Hl)
  ushortT (*Gl)[72]  = (ushortT(*)[72])(ovl + 34816);  // 9216

  const int t = threadIdx.x;
  const int bid = blockIdx.x;
  const int bc = bid & 31, dg = bid >> 5;   // chunk idx, d-slice idx
  const int b = bc >> 4, c = bc & 15;
  const int l = t & 63, w = t >> 6;
  const size_t rowbase = (size_t)(b * S_LEN + c * CL) * DI + dg * 64;
  const int brow = b * S_LEN + c * CL;
  const int d0 = dg * 64;

  // ---- phase 1: stage Btl / dtl / Wl
#pragma unroll
  for (int j = 0; j < 8; ++j) {
    int idx4 = j * 256 + t;
    int s = idx4 >> 5, n4 = (idx4 & 31) * 4;
    float4 v = *(const float4*)&dbl[(size_t)(bc * 64 + s) * 288 + 32 + n4];
    Btl[n4][s] = f2b(v.x); Btl[n4 + 1][s] = f2b(v.y);
    Btl[n4 + 2][s] = f2b(v.z); Btl[n4 + 3][s] = f2b(v.w);
  }
#pragma unroll
  for (int j = 0; j < 2; ++j) {
    int idx4 = j * 256 + t;
    int s = idx4 >> 3, k4 = (idx4 & 7) * 4;
    *(float4*)&dtl[s][k4] = *(const float4*)&dbl[(size_t)(bc * 64 + s) * 288 + k4];
  }
#pragma unroll
  for (int j = 0; j < 4; ++j) {
    int idx2 = j * 256 + t;
    int k = idx2 >> 5, d2 = (idx2 & 31) * 2;
    float2 v = *(const float2*)&W_dt[(size_t)k * DI + dg * 64 + d2];
    Wl[k][d2] = f2b(v.x); Wl[k][d2 + 1] = f2b(v.y);
  }
  __syncthreads();

  // dt-proj: lane = d, wave = s-quarter; W hoisted to registers
  {
    int d = t & 63, sq = t >> 6;
    float wreg[32];
#pragma unroll
    for (int k = 0; k < 32; ++k) wreg[k] = b2f(Wl[k][d]);
    float bias = b_dt[dg * 64 + d] + 1e-4f;
#pragma unroll 4
    for (int j = 0; j < 16; ++j) {
      int s = sq * 16 + j;
      float acc = bias;
#pragma unroll
      for (int k = 0; k < 32; ++k) acc = fmaf(dtl[s][k], wreg[k], acc);
      acc = (acc > 20.f) ? acc : log1pf(expf(acc));
      acc = fminf(fmaxf(acc, 0.001f), 0.1f);
      Dl[d][s] = 1.f - acc;
    }
  }
  __syncthreads();

  // cumprod + dend
  if (t < 64) {
    float cum = 1.f;
#pragma unroll 16
    for (int s = 0; s < CL; ++s) { cum *= Dl[t][s]; Dl[t][s] = cum; }
    dend[((size_t)(b * DI) + dg * 64 + t) * 16 + c] = cum;
  }
  __syncthreads();

  // ut build (stays in LDS)
#pragma unroll
  for (int j = 0; j < 2; ++j) {
    int idx8 = j * 256 + t;
    int s = idx8 >> 3, d8 = (idx8 & 7) * 8;
    float4 raw = *(const float4*)&u_bf[rowbase + (size_t)s * DI + d8];
    const ushortT* up = (const ushortT*)&raw;
#pragma unroll
    for (int k = 0; k < 8; ++k)
      utl[d8 + k][s] = f2b(b2f(up[k]) / Dl[d8 + k][s]);
  }
  __syncthreads();

  // Z = utl @ Btl^T (MFMA) -> zb global, layout [b][c][d][n]
  {
    f32x4 acc[8] = {};
#pragma unroll
    for (int kk = 0; kk < 2; ++kk) {
      short8 a = *(const short8*)&utl[w * 16 + (l & 15)][kk * 32 + (l >> 4) * 8];
#pragma unroll
      for (int n = 0; n < 8; ++n) {
        short8 bb = *(const short8*)&Btl[n * 16 + (l & 15)][kk * 32 + (l >> 4) * 8];
        acc[n] = __builtin_amdgcn_mfma_f32_16x16x32_bf16(a, bb, acc[n], 0, 0, 0);
      }
    }
#pragma unroll
    for (int n = 0; n < 8; ++n) {
      int gn = n * 16 + (l & 15);
#pragma unroll
      for (int i = 0; i < 4; ++i) {
        int d = dg * 64 + w * 16 + (l >> 4) * 4 + i;
        zb[(((size_t)(b * NC + c)) * DI + d) * 128 + gn] = f2b(acc[n][i]);
      }
    }
  }
  __syncthreads();  // all waves done reading Btl -> ovl reusable

  // stage Cl/Bl + compute G while other blocks finish phase 1
#pragma unroll
  for (int j = 0; j < 16; ++j) {
    int idx4 = j * 256 + t;
    int row = idx4 >> 6, c4 = (idx4 & 63) * 4;
    float4 v = *(const float4*)&dbl[(size_t)(bc * 64 + row) * 288 + 32 + c4];
    ushortT o0 = f2b(v.x), o1 = f2b(v.y), o2 = f2b(v.z), o3 = f2b(v.w);
    if (c4 < 128) { Bl[row][c4] = o0; Bl[row][c4+1] = o1; Bl[row][c4+2] = o2; Bl[row][c4+3] = o3; }
    else { int cc = c4 - 128; Cl[row][cc] = o0; Cl[row][cc+1] = o1; Cl[row][cc+2] = o2; Cl[row][cc+3] = o3; }
  }
  __syncthreads();
  {
    f32x4 gacc[4] = {};
#pragma unroll
    for (int kk = 0; kk < 4; ++kk) {
      short8 a = *(const short8*)&Cl[w * 16 + (l & 15)][kk * 32 + (l >> 4) * 8];
#pragma unroll
      for (int nf = 0; nf < 4; ++nf) {
        short8 bb = *(const short8*)&Bl[nf * 16 + (l & 15)][kk * 32 + (l >> 4) * 8];
        gacc[nf] = __builtin_amdgcn_mfma_f32_16x16x32_bf16(a, bb, gacc[nf], 0, 0, 0);
      }
    }
#pragma unroll
    for (int nf = 0; nf < 4; ++nf) {
      int s = nf * 16 + (l & 15);
#pragma unroll
      for (int i = 0; i < 4; ++i) {
        int tr = w * 16 + (l >> 4) * 4 + i;
        Gl[tr][s] = f2b((s <= tr) ? gacc[nf][i] : 0.f);
      }
    }
  }

  __threadfence();
  cg::this_grid().sync();

  // ---- phase 2: chunk-boundary chain (block handles wids bid*4..bid*4+3)
  {
    int wid = bid * 4 + w;
    int b2 = wid >> 10, d2 = wid & (DI - 1);
    float h0 = 0.f, h1 = 0.f;
#pragma unroll
    for (int c2 = 0; c2 < NC; ++c2) {
      float dd = dend[(size_t)wid * 16 + c2];
      size_t addr = (((size_t)(b2 * NC + c2)) * DI + d2) * 128 + 2 * l;
      ushort2 z2 = *(const ushort2*)&zb[addr];
      ushort2 he;
      he.x = f2b(h0); he.y = f2b(h1);
      *(ushort2*)&hstb[addr] = he;
      h0 = dd * (h0 + b2f(z2.x));
      h1 = dd * (h1 + b2f(z2.y));
    }
  }

  __threadfence();
  cg::this_grid().sync();

  // ---- phase 3: stage Hl (over Bl), then Y MFMAs
  ushortT (*Hl)[136] = Bl;
#pragma unroll
  for (int j = 0; j < 4; ++j) {
    int idx4 = j * 256 + t;
    int dr = idx4 >> 4, n8 = (idx4 & 15) * 8;
    float4 v = *(const float4*)&hstb[(((size_t)(b * NC + c)) * DI + d0 + dr) * 128 + n8];
    *(float4*)&Hl[dr][n8] = v;
  }
  __syncthreads();
  f32x4 acc[4] = {};
  // K=64 (s): A = Gl rows, B = utl rows (both LDS-resident)
#pragma unroll
  for (int kk = 0; kk < 2; ++kk) {
    short8 a = *(const short8*)&Gl[w * 16 + (l & 15)][kk * 32 + (l >> 4) * 8];
#pragma unroll
    for (int n = 0; n < 4; ++n) {
      short8 bb = *(const short8*)&utl[n * 16 + (l & 15)][kk * 32 + (l >> 4) * 8];
      acc[n] = __builtin_amdgcn_mfma_f32_16x16x32_bf16(a, bb, acc[n], 0, 0, 0);
    }
  }
  // K=128 (n-state): A = Cl rows, B = Hl rows
#pragma unroll
  for (int kk = 0; kk < 4; ++kk) {
    short8 a = *(const short8*)&Cl[w * 16 + (l & 15)][kk * 32 + (l >> 4) * 8];
#pragma unroll
    for (int n = 0; n < 4; ++n) {
      short8 bb = *(const short8*)&Hl[n * 16 + (l & 15)][kk * 32 + (l >> 4) * 8];
      acc[n] = __builtin_amdgcn_mfma_f32_16x16x32_bf16(a, bb, acc[n], 0, 0, 0);
    }
  }
#pragma unroll
  for (int n = 0; n < 4; ++n) {
    int dl = n * 16 + (l & 15);
    int d = d0 + dl;
#pragma unroll
    for (int i = 0; i < 4; ++i) {
      int tl = w * 16 + (l >> 4) * 4 + i;
      int gr = brow + tl;
      float Dv = Dl[dl][tl];
      float res = b2f(xr_bf[(size_t)gr * 2048 + 1024 + d]);
      yr[(size_t)gr * DI + d] = f2b(acc[n][i] * Dv + res);
    }
  }
}

extern "C" void kernel_launch(void* const* d_in, const int* in_sizes, int n_in,
                              void* d_out, int out_size, void* d_ws, size_t ws_size,
                              hipStream_t stream) {
  const float* x      = (const float*)d_in[0];
  const float* W_in   = (const float*)d_in[1];
  const float* conv_w = (const float*)d_in[2];
  const float* conv_b = (const float*)d_in[3];
  const float* W_x    = (const float*)d_in[4];
  const float* W_dt   = (const float*)d_in[5];
  const float* b_dt   = (const float*)d_in[6];
  const float* W_out  = (const float*)d_in[7];
  float* out = (float*)d_out;
  float* ws = (float*)d_ws;

  // workspace (float units), all disjoint
  ushortT* xr_bf = (ushortT*)ws;                  // [2048,2048] bf16
  ushortT* u_bf  = (ushortT*)(ws + 2097152);      // [2048,1024] bf16
  float*   dbl   = ws + 3145728;                  // [2048,288] fp32
  float*   dend  = ws + 3735552;                  // [2048,1024->16] fp32 (32K)
  ushortT* zb    = (ushortT*)(ws + 6881280);      // [2,16,1024,128] bf16
  ushortT* hstb  = (ushortT*)(ws + 8978432);      // [2,16,1024,128] bf16
  ushortT* x_bf  = (ushortT*)(ws + 11075584);     // [2048,512] bf16
  ushortT* Wt_in = (ushortT*)(ws + 11599872);     // [2048,512] bf16
  ushortT* Wt_x  = (ushortT*)(ws + 12124160);     // [384,1024] bf16
  ushortT* Wt_out= (ushortT*)(ws + 12320768);     // [512,1024] bf16
  ushortT* yr_bf = (ushortT*)(ws + 12582912);     // [2048,1024] bf16

  dim3 blk(256);
  // 1) weight transposes + x cvt
  prep_all<<<2944, dim3(32, 8), 0, stream>>>(W_in, W_x, W_out, x,
                                             Wt_in, Wt_x, Wt_out, x_bf);
  // 2) in-proj: xr = x @ W_in (bf16)  M=2048 N=2048 K=512; 64-tile 32x32=1024
  gemm64<1><<<1024, blk, 0, stream>>>(x_bf, Wt_in, xr_bf, 2 * DI, DM, 2 * DI, 32);
  // 3) conv -> u (bf16)
  conv_kernel<<<2048, blk, 0, stream>>>(xr_bf, conv_w, conv_b, u_bf);
  // 4) x-proj: dbl = u @ W_x (fp32)  M=2048 N=288 K=1024; 64-tile 5x32=160
  gemm64<0><<<160, blk, 0, stream>>>(u_bf, Wt_x, dbl, DTR + 2 * DS, DI, DTR + 2 * DS, 5);
  // 5) fused scan tail (cooperative: 512 blocks, 2/CU, 69.5 KB LDS)
  {
    void* kargs[] = {(void*)&dbl, (void*)&W_dt, (void*)&b_dt, (void*)&u_bf,
                     (void*)&dend, (void*)&zb, (void*)&hstb, (void*)&xr_bf,
                     (void*)&yr_bf};
    hipLaunchCooperativeKernel((const void*)scan_fused, dim3(512), dim3(256),
                               kargs, 0, stream);
  }
  // 6) out-proj: out = yr @ W_out (fp32)  M=2048 N=512 K=1024; 64-tile 8x32=256
  gemm64<0><<<256, blk, 0, stream>>>(yr_bf, Wt_out, out, DM, DI, DM, 8);
}

// Round 16
// 94.284 us; speedup vs baseline: 2.8339x; 2.8339x over previous
//
#include <hip/hip_runtime.h>
#include <math.h>

#define S_LEN 1024
#define BATCH 2
#define DM 512
#define DI 1024
#define DS 128
#define DTR 32
#define CL 64            // chunk length
#define NC (S_LEN / CL)  // 16 chunks

typedef unsigned short ushortT;
typedef __attribute__((ext_vector_type(8))) short short8;
typedef __attribute__((ext_vector_type(4))) float f32x4;

__device__ __forceinline__ ushortT f2b(float f) {
  unsigned u = __builtin_bit_cast(unsigned, f);
  unsigned r = (u + 0x7fff + ((u >> 16) & 1)) >> 16;  // RNE
  return (ushortT)r;
}
__device__ __forceinline__ float b2f(ushortT h) {
  return __builtin_bit_cast(float, (unsigned)h << 16);
}

#define GLOAD16(g, l)                                                     \
  __builtin_amdgcn_global_load_lds(                                       \
      (const __attribute__((address_space(1))) void*)(g),                 \
      (__attribute__((address_space(3))) void*)(l), 16, 0, 0)

// ---- gemm64: 64x64 tile, 4 waves (2x2, each 32x32), XCD-swizzled flat grid,
// double-buffered LDS. MODE 0: fp32 out; 1: bf16 out.
// NOTE (r15 lesson): cooperative grid.sync on MI355X costs ~100us; the
// 8-dispatch pipeline below is faster than any grid-sync fusion of it.
template<int MODE>
__global__ __launch_bounds__(256) void gemm64(
    const ushortT* __restrict__ A, const ushortT* __restrict__ Bt,
    void* __restrict__ Cout, int N, int K, int ldc, int nbx) {
  __shared__ ushortT As[2][64 * 32];
  __shared__ ushortT Bs[2][64 * 32];
  const int nwg = gridDim.x;
  const int bid = blockIdx.x;
  const int flat = (bid & 7) * (nwg >> 3) + (bid >> 3);
  const int bxi = flat % nbx, byi = flat / nbx;
  const int bm = byi * 64, bn = bxi * 64;
  const int tid = threadIdx.x;
  const int l = tid & 63, w = tid >> 6;
  const int wr = w >> 1, wc = w & 1;
  const int srow = tid >> 2, scol = (tid & 3) * 8;
  const ushortT* gA = A + (size_t)(bm + srow) * K + scol;
  const ushortT* gB = Bt + (size_t)(bn + srow) * K + scol;
  f32x4 acc[2][2] = {};
  const int nt = K >> 5;
  GLOAD16(gA, &As[0][(size_t)tid * 8]);
  GLOAD16(gB, &Bs[0][(size_t)tid * 8]);
  __syncthreads();
  int cur = 0;
  for (int t = 0; t < nt; ++t) {
    if (t + 1 < nt) {
      GLOAD16(gA + (t + 1) * 32, &As[cur ^ 1][(size_t)tid * 8]);
      GLOAD16(gB + (t + 1) * 32, &Bs[cur ^ 1][(size_t)tid * 8]);
    }
    short8 a[2], b[2];
#pragma unroll
    for (int m = 0; m < 2; ++m)
      a[m] = *(const short8*)&As[cur][(wr * 32 + m * 16 + (l & 15)) * 32 + (l >> 4) * 8];
#pragma unroll
    for (int n = 0; n < 2; ++n)
      b[n] = *(const short8*)&Bs[cur][(wc * 32 + n * 16 + (l & 15)) * 32 + (l >> 4) * 8];
#pragma unroll
    for (int m = 0; m < 2; ++m)
#pragma unroll
      for (int n = 0; n < 2; ++n)
        acc[m][n] = __builtin_amdgcn_mfma_f32_16x16x32_bf16(a[m], b[n], acc[m][n], 0, 0, 0);
    __syncthreads();
    cur ^= 1;
  }
#pragma unroll
  for (int m = 0; m < 2; ++m) {
    int grow = bm + wr * 32 + m * 16 + (l >> 4) * 4;
#pragma unroll
    for (int n = 0; n < 2; ++n) {
      int gcol = bn + wc * 32 + n * 16 + (l & 15);
      if (gcol >= N) continue;
#pragma unroll
      for (int i = 0; i < 4; ++i) {
        float v = acc[m][n][i];
        if (MODE == 1)
          ((ushortT*)Cout)[(size_t)(grow + i) * ldc + gcol] = f2b(v);
        else
          ((float*)Cout)[(size_t)(grow + i) * ldc + gcol] = v;
      }
    }
  }
}

// ---- prep_all: weight transposes (fp32->bf16, [K,N]->[Npad,K], ushort4
// stores) + x cvt.
__global__ __launch_bounds__(256) void prep_all(
    const float* __restrict__ W_in, const float* __restrict__ W_x,
    const float* __restrict__ W_out, const float* __restrict__ x,
    ushortT* __restrict__ Wt_in, ushortT* __restrict__ Wt_x,
    ushortT* __restrict__ Wt_out, ushortT* __restrict__ x_bf) {
  __shared__ float tb[32][33];
  int bid = blockIdx.x;
  int tx = threadIdx.x, ty = threadIdx.y;  // (32,8)
  const float* in; ushortT* out; int K, N, bx, by;
  if (bid < 1024)      { in = W_in;  out = Wt_in;  K = 512;  N = 2048; bx = bid & 63; by = bid >> 6; }
  else if (bid < 1408) { int t2 = bid - 1024; in = W_x;   out = Wt_x;   K = 1024; N = 288;  bx = t2 % 12; by = t2 / 12; }
  else if (bid < 1920) { int t2 = bid - 1408; in = W_out; out = Wt_out; K = 1024; N = 512;  bx = t2 % 16; by = t2 / 16; }
  else {
    int i = (bid - 1920) * 256 + ty * 32 + tx;
    float4 v = ((const float4*)x)[i];
    ushort4 o; o.x = f2b(v.x); o.y = f2b(v.y); o.z = f2b(v.z); o.w = f2b(v.w);
    ((ushort4*)x_bf)[i] = o;
    return;
  }
  int n0 = bx * 32, k0 = by * 32;
  int flat = ty * 32 + tx;
  int r = flat >> 3, c4 = (flat & 7) * 4;  // 32 rows x 8 ushort4 cols
  if (n0 < N) {
#pragma unroll
    for (int i = 0; i < 4; ++i)
      tb[ty + 8 * i][tx] = in[(size_t)(k0 + ty + 8 * i) * N + n0 + tx];
    __syncthreads();
    ushort4 o;
    o.x = f2b(tb[c4][r]);
    o.y = f2b(tb[c4 + 1][r]);
    o.z = f2b(tb[c4 + 2][r]);
    o.w = f2b(tb[c4 + 3][r]);
    *(ushort4*)&out[(size_t)(n0 + r) * K + k0 + c4] = o;
  } else {
    ushort4 z; z.x = 0; z.y = 0; z.z = 0; z.w = 0;
    *(ushort4*)&out[(size_t)(n0 + r) * K + k0 + c4] = z;
  }
}

// ---- depthwise causal conv, 4 d per thread (ushort4) ------------------------
__global__ __launch_bounds__(256) void conv_kernel(
    const ushortT* __restrict__ xr, const float* __restrict__ w,
    const float* __restrict__ b, ushortT* __restrict__ u) {
  int idx = blockIdx.x * blockDim.x + threadIdx.x;
  int g = idx & 255;
  int s = (idx >> 8) & (S_LEN - 1);
  int bb = idx >> 18;
  int d = g * 4;
  float4 bias = *(const float4*)&b[d];
  float4 w0 = *(const float4*)&w[(d + 0) * 4];
  float4 w1 = *(const float4*)&w[(d + 1) * 4];
  float4 w2 = *(const float4*)&w[(d + 2) * 4];
  float4 w3 = *(const float4*)&w[(d + 3) * 4];
  float a0 = bias.x, a1 = bias.y, a2 = bias.z, a3 = bias.w;
  const ushortT* xs = xr + (size_t)(bb * S_LEN) * (2 * DI) + d;
#pragma unroll
  for (int k = 0; k < 4; ++k) {
    int si = s - 3 + k;
    if (si >= 0) {
      ushort4 v = *(const ushort4*)&xs[(size_t)si * (2 * DI)];
      float wk0 = ((const float*)&w0)[k], wk1 = ((const float*)&w1)[k];
      float wk2 = ((const float*)&w2)[k], wk3 = ((const float*)&w3)[k];
      a0 = fmaf(b2f(v.x), wk0, a0);
      a1 = fmaf(b2f(v.y), wk1, a1);
      a2 = fmaf(b2f(v.z), wk2, a2);
      a3 = fmaf(b2f(v.w), wk3, a3);
    }
  }
  ushort4 o; o.x = f2b(a0); o.y = f2b(a1); o.z = f2b(a2); o.w = f2b(a3);
  *(ushort4*)&u[(size_t)idx * 4] = o;
}

// ---- megachunk: per (dg, bc) 64-d slice: dt-proj + softplus/clip + cumprod
//      + ut + Z = ut @ B^T. D stored bf16; zb layout [b][c][d][n]. ----------
__global__ __launch_bounds__(256) void megachunk(
    const float* __restrict__ dbl, const float* __restrict__ W_dt,
    const float* __restrict__ b_dt, const ushortT* __restrict__ u_bf,
    ushortT* __restrict__ D, ushortT* __restrict__ ut,
    ushortT* __restrict__ zb) {
  __shared__ ushortT Btl[128][72];   // B^T[n][s]
  __shared__ float   Dl[64][66];     // om -> cumprod D, [d][s]
  __shared__ ushortT utl[64][72];    // ut[d][s]
  __shared__ float   dtl[64][36];    // dbl[:,0:32]
  __shared__ ushortT Wl[32][68];     // W_dt slice bf16 [k][d]
  const int t = threadIdx.x;
  const int dg = blockIdx.x, bc = blockIdx.y;
  const int b = bc >> 4, c = bc & 15;
  const size_t rowbase = (size_t)(b * S_LEN + c * CL) * DI + dg * 64;

#pragma unroll
  for (int j = 0; j < 8; ++j) {
    int idx4 = j * 256 + t;
    int s = idx4 >> 5, n4 = (idx4 & 31) * 4;
    float4 v = *(const float4*)&dbl[(size_t)(bc * 64 + s) * 288 + 32 + n4];
    Btl[n4][s] = f2b(v.x); Btl[n4 + 1][s] = f2b(v.y);
    Btl[n4 + 2][s] = f2b(v.z); Btl[n4 + 3][s] = f2b(v.w);
  }
#pragma unroll
  for (int j = 0; j < 2; ++j) {
    int idx4 = j * 256 + t;
    int s = idx4 >> 3, k4 = (idx4 & 7) * 4;
    *(float4*)&dtl[s][k4] = *(const float4*)&dbl[(size_t)(bc * 64 + s) * 288 + k4];
  }
#pragma unroll
  for (int j = 0; j < 4; ++j) {
    int idx2 = j * 256 + t;
    int k = idx2 >> 5, d2 = (idx2 & 31) * 2;
    float2 v = *(const float2*)&W_dt[(size_t)k * DI + dg * 64 + d2];
    Wl[k][d2] = f2b(v.x); Wl[k][d2 + 1] = f2b(v.y);
  }
  __syncthreads();

  {
    int d = t & 63, sq = t >> 6;
    float wreg[32];
#pragma unroll
    for (int k = 0; k < 32; ++k) wreg[k] = b2f(Wl[k][d]);
    float bias = b_dt[dg * 64 + d] + 1e-4f;
#pragma unroll 4
    for (int j = 0; j < 16; ++j) {
      int s = sq * 16 + j;
      float acc = bias;
#pragma unroll
      for (int k = 0; k < 32; ++k) acc = fmaf(dtl[s][k], wreg[k], acc);
      acc = (acc > 20.f) ? acc : log1pf(expf(acc));
      acc = fminf(fmaxf(acc, 0.001f), 0.1f);
      Dl[d][s] = 1.f - acc;
    }
  }
  __syncthreads();

  if (t < 64) {
    float cum = 1.f;
#pragma unroll 16
    for (int s = 0; s < CL; ++s) { cum *= Dl[t][s]; Dl[t][s] = cum; }
  }
  __syncthreads();

  // ut build
#pragma unroll
  for (int j = 0; j < 2; ++j) {
    int idx8 = j * 256 + t;
    int s = idx8 >> 3, d8 = (idx8 & 7) * 8;
    float4 raw = *(const float4*)&u_bf[rowbase + (size_t)s * DI + d8];
    const ushortT* up = (const ushortT*)&raw;
#pragma unroll
    for (int k = 0; k < 8; ++k)
      utl[d8 + k][s] = f2b(b2f(up[k]) / Dl[d8 + k][s]);
  }
  __syncthreads();

  // Z = utl @ Btl^T (MFMA), global writes after; zb layout [b][c][d][n]
  {
    const int l = t & 63, w = t >> 6;
    f32x4 acc[8] = {};
#pragma unroll
    for (int kk = 0; kk < 2; ++kk) {
      short8 a = *(const short8*)&utl[w * 16 + (l & 15)][kk * 32 + (l >> 4) * 8];
#pragma unroll
      for (int n = 0; n < 8; ++n) {
        short8 bb = *(const short8*)&Btl[n * 16 + (l & 15)][kk * 32 + (l >> 4) * 8];
        acc[n] = __builtin_amdgcn_mfma_f32_16x16x32_bf16(a, bb, acc[n], 0, 0, 0);
      }
    }
#pragma unroll
    for (int n = 0; n < 8; ++n) {
      int gn = n * 16 + (l & 15);
#pragma unroll
      for (int i = 0; i < 4; ++i) {
        int d = dg * 64 + w * 16 + (l >> 4) * 4 + i;
        zb[(((size_t)(b * NC + c)) * DI + d) * 128 + gn] = f2b(acc[n][i]);
      }
    }
  }

  // D global write bf16 [s][d] (ushort8 = float4)
#pragma unroll
  for (int j = 0; j < 2; ++j) {
    int idx8 = j * 256 + t;
    int s = idx8 >> 3, d8 = (idx8 & 7) * 8;
    float4 v; ushortT* vp = (ushortT*)&v;
#pragma unroll
    for (int k = 0; k < 8; ++k) vp[k] = f2b(Dl[d8 + k][s]);
    *(float4*)&D[rowbase + (size_t)s * DI + d8] = v;
  }
  // ut global write (rows d)
#pragma unroll
  for (int j = 0; j < 2; ++j) {
    int idx8 = j * 256 + t;
    int d = idx8 >> 3, s8 = (idx8 & 7) * 8;
    float4 v; ushortT* vp = (ushortT*)&v;
#pragma unroll
    for (int k = 0; k < 8; ++k) vp[k] = utl[d][s8 + k];
    *(float4*)&ut[((size_t)bc * DI + dg * 64 + d) * CL + s8] = v;
  }
}

// ---- pass2: h_entry chain over chunks (layout [b][c][d][n], D bf16) --------
__global__ __launch_bounds__(256) void scan_pass2(
    const ushortT* __restrict__ zb, const ushortT* __restrict__ D,
    ushortT* __restrict__ hstb) {
  int wid = (blockIdx.x * blockDim.x + threadIdx.x) >> 6;  // 0..2047 = b*DI+d
  int lane = threadIdx.x & 63;
  int b = wid >> 10, d = wid & (DI - 1);
  float h0 = 0.f, h1 = 0.f;
#pragma unroll
  for (int c = 0; c < NC; ++c) {
    float dend = b2f(D[((size_t)(b * S_LEN + c * CL + CL - 1)) * DI + d]);
    size_t addr = (((size_t)(b * NC + c)) * DI + d) * 128 + 2 * lane;
    ushort2 z2 = *(const ushort2*)&zb[addr];
    ushort2 he;
    he.x = f2b(h0); he.y = f2b(h1);
    *(ushort2*)&hstb[addr] = he;
    h0 = dend * (h0 + b2f(z2.x));
    h1 = dend * (h1 + b2f(z2.y));
  }
}

// ---- Y (64-d blocks): stage B,C + ut + hstb + D tiles in LDS (coalesced);
//      G = tril(C.B^T); yr[t,d] = bf16( D*( G@ut + C@hstb ) + res ) ---------
__global__ __launch_bounds__(256) void gemm_y(
    const float* __restrict__ dbl, const ushortT* __restrict__ ut,
    const ushortT* __restrict__ hstb, const ushortT* __restrict__ D,
    const ushortT* __restrict__ xr_bf, ushortT* __restrict__ yr) {
  __shared__ ushortT Bl[64][136];
  __shared__ ushortT Cl[64][136];
  __shared__ ushortT Gl[64][72];
  __shared__ ushortT Ul[64][72];    // ut tile [d][s]
  __shared__ ushortT Hl[64][136];   // hstb tile [d][n]
  __shared__ ushortT Dl2[64][72];   // D tile [t][d] bf16
  const int tid = threadIdx.x;
  const int l = tid & 63, w = tid >> 6;
  const int bc = blockIdx.y, d0 = blockIdx.x * 64;
  const int b = bc >> 4, c = bc & 15;
  const int brow = b * S_LEN + c * CL;
#pragma unroll
  for (int j = 0; j < 2; ++j) {
    int idx4 = j * 256 + tid;
    int dr = idx4 >> 3, s8 = (idx4 & 7) * 8;
    float4 v = *(const float4*)&ut[((size_t)bc * DI + d0 + dr) * CL + s8];
    *(float4*)&Ul[dr][s8] = v;
  }
#pragma unroll
  for (int j = 0; j < 4; ++j) {
    int idx4 = j * 256 + tid;
    int dr = idx4 >> 4, n8 = (idx4 & 15) * 8;
    float4 v = *(const float4*)&hstb[(((size_t)(b * NC + c)) * DI + d0 + dr) * 128 + n8];
    *(float4*)&Hl[dr][n8] = v;
  }
#pragma unroll
  for (int j = 0; j < 2; ++j) {
    int idx4 = j * 256 + tid;
    int tr = idx4 >> 3, d8 = (idx4 & 7) * 8;
    float4 v = *(const float4*)&D[((size_t)(brow + tr)) * DI + d0 + d8];
    *(float4*)&Dl2[tr][d8] = v;
  }
#pragma unroll
  for (int j = 0; j < 16; ++j) {
    int idx4 = j * 256 + tid;
    int row = idx4 >> 6, c4 = (idx4 & 63) * 4;
    float4 v = *(const float4*)&dbl[(size_t)(bc * 64 + row) * 288 + 32 + c4];
    ushortT o0 = f2b(v.x), o1 = f2b(v.y), o2 = f2b(v.z), o3 = f2b(v.w);
    if (c4 < 128) { Bl[row][c4] = o0; Bl[row][c4+1] = o1; Bl[row][c4+2] = o2; Bl[row][c4+3] = o3; }
    else { int cc = c4 - 128; Cl[row][cc] = o0; Cl[row][cc+1] = o1; Cl[row][cc+2] = o2; Cl[row][cc+3] = o3; }
  }
  __syncthreads();
  {
    f32x4 gacc[4] = {};
#pragma unroll
    for (int kk = 0; kk < 4; ++kk) {
      short8 a = *(const short8*)&Cl[w * 16 + (l & 15)][kk * 32 + (l >> 4) * 8];
#pragma unroll
      for (int nf = 0; nf < 4; ++nf) {
        short8 bb = *(const short8*)&Bl[nf * 16 + (l & 15)][kk * 32 + (l >> 4) * 8];
        gacc[nf] = __builtin_amdgcn_mfma_f32_16x16x32_bf16(a, bb, gacc[nf], 0, 0, 0);
      }
    }
#pragma unroll
    for (int nf = 0; nf < 4; ++nf) {
      int s = nf * 16 + (l & 15);
#pragma unroll
      for (int i = 0; i < 4; ++i) {
        int tr = w * 16 + (l >> 4) * 4 + i;
        Gl[tr][s] = f2b((s <= tr) ? gacc[nf][i] : 0.f);
      }
    }
  }
  __syncthreads();
  f32x4 acc[4] = {};
#pragma unroll
  for (int kk = 0; kk < 2; ++kk) {
    short8 a = *(const short8*)&Gl[w * 16 + (l & 15)][kk * 32 + (l >> 4) * 8];
#pragma unroll
    for (int n = 0; n < 4; ++n) {
      short8 bb = *(const short8*)&Ul[n * 16 + (l & 15)][kk * 32 + (l >> 4) * 8];
      acc[n] = __builtin_amdgcn_mfma_f32_16x16x32_bf16(a, bb, acc[n], 0, 0, 0);
    }
  }
#pragma unroll
  for (int kk = 0; kk < 4; ++kk) {
    short8 a = *(const short8*)&Cl[w * 16 + (l & 15)][kk * 32 + (l >> 4) * 8];
#pragma unroll
    for (int n = 0; n < 4; ++n) {
      short8 bb = *(const short8*)&Hl[n * 16 + (l & 15)][kk * 32 + (l >> 4) * 8];
      acc[n] = __builtin_amdgcn_mfma_f32_16x16x32_bf16(a, bb, acc[n], 0, 0, 0);
    }
  }
#pragma unroll
  for (int n = 0; n < 4; ++n) {
    int dl = n * 16 + (l & 15);
    int d = d0 + dl;
#pragma unroll
    for (int i = 0; i < 4; ++i) {
      int tl = w * 16 + (l >> 4) * 4 + i;
      int gr = brow + tl;
      float Dv = b2f(Dl2[tl][dl]);
      float res = b2f(xr_bf[(size_t)gr * 2048 + 1024 + d]);
      yr[(size_t)gr * DI + d] = f2b(acc[n][i] * Dv + res);
    }
  }
}

extern "C" void kernel_launch(void* const* d_in, const int* in_sizes, int n_in,
                              void* d_out, int out_size, void* d_ws, size_t ws_size,
                              hipStream_t stream) {
  const float* x      = (const float*)d_in[0];
  const float* W_in   = (const float*)d_in[1];
  const float* conv_w = (const float*)d_in[2];
  const float* conv_b = (const float*)d_in[3];
  const float* W_x    = (const float*)d_in[4];
  const float* W_dt   = (const float*)d_in[5];
  const float* b_dt   = (const float*)d_in[6];
  const float* W_out  = (const float*)d_in[7];
  float* out = (float*)d_out;
  float* ws = (float*)d_ws;

  // workspace (float units), all disjoint
  ushortT* xr_bf = (ushortT*)ws;                  // [2048,2048] bf16
  ushortT* u_bf  = (ushortT*)(ws + 2097152);      // [2048,1024] bf16
  float*   dbl   = ws + 3145728;                  // [2048,288] fp32
  ushortT* Dc    = (ushortT*)(ws + 3735552);      // [2048,1024] bf16
  ushortT* ut    = (ushortT*)(ws + 5832704);      // [32,1024,64] bf16
  ushortT* zb    = (ushortT*)(ws + 6881280);      // [2,16,1024,128] bf16
  ushortT* hstb  = (ushortT*)(ws + 8978432);      // [2,16,1024,128] bf16
  ushortT* x_bf  = (ushortT*)(ws + 11075584);     // [2048,512] bf16
  ushortT* Wt_in = (ushortT*)(ws + 11599872);     // [2048,512] bf16
  ushortT* Wt_x  = (ushortT*)(ws + 12124160);     // [384,1024] bf16
  ushortT* Wt_out= (ushortT*)(ws + 12320768);     // [512,1024] bf16
  ushortT* yr_bf = (ushortT*)(ws + 12582912);     // [2048,1024] bf16

  dim3 blk(256);
  // 1) weight transposes + x cvt
  prep_all<<<2944, dim3(32, 8), 0, stream>>>(W_in, W_x, W_out, x,
                                             Wt_in, Wt_x, Wt_out, x_bf);
  // 2) in-proj: xr = x @ W_in (bf16)  M=2048 N=2048 K=512; 64-tile 32x32=1024
  gemm64<1><<<1024, blk, 0, stream>>>(x_bf, Wt_in, xr_bf, 2 * DI, DM, 2 * DI, 32);
  // 3) conv -> u (bf16)
  conv_kernel<<<2048, blk, 0, stream>>>(xr_bf, conv_w, conv_b, u_bf);
  // 4) x-proj: dbl = u @ W_x (fp32)  M=2048 N=288 K=1024; 64-tile 5x32=160
  gemm64<0><<<160, blk, 0, stream>>>(u_bf, Wt_x, dbl, DTR + 2 * DS, DI, DTR + 2 * DS, 5);
  // 5) megachunk: dt-proj + decay + ut + Z  (512 blocks, 2/CU)
  megachunk<<<dim3(16, 32), blk, 0, stream>>>(dbl, W_dt, b_dt, u_bf, Dc, ut, zb);
  // 6) chunk-boundary combine -> hstb (entry states, bf16)
  scan_pass2<<<512, blk, 0, stream>>>(zb, Dc, hstb);
  // 7) Y = D*(G@ut + C@h_entry) + res -> yr_bf  (512 blocks)
  gemm_y<<<dim3(16, 32), blk, 0, stream>>>(dbl, ut, hstb, Dc, xr_bf, yr_bf);
  // 8) out-proj: out = yr @ W_out (fp32)  M=2048 N=512 K=1024; 64-tile 8x32=256
  gemm64<0><<<256, blk, 0, stream>>>(yr_bf, Wt_out, out, DM, DI, DM, 8);
}